// Round 2
// baseline (647.028 us; speedup 1.0000x reference)
//
#include <hip/hip_runtime.h>

// HarmonicLowering: out[b, k*C+c, f, t] = w*x[b,c,i0,t] + (1-w)*x[b,c,i1,t]
//   prod = f*(k+1); i0 = prod>>2; w = 1 - (prod&3)/4; i1 = min(i0+1, F-1)
// Shapes: x (8,32,256,512) f32 -> out (8,128,256,512) f32.
//
// v2: each thread produces an f-group of 4 outputs (f = 4j..4j+3) for one
// (b,k,c,tv). Per-k row sharing cuts loads from 8/group to 2-4/group:
//   k=0: rows {j, j+1}        w = 1, .75, .5, .25
//   k=1: rows {2j..2j+2}      w = 1, .5, 1, .5
//   k=2: rows {3j..3j+3}      w = 1, .25, .5, .75
//   k=3: rows {4j..4j+3}      pure copy (w == 1)
// The i1 clamp (min(i0+1,255)) only triggers where (1-w)==0, so it is dropped.
// k sits at bits 18-19 of the flat id -> block-uniform branch, no divergence.
// Stores are nontemporal: out is write-once, keep LLC free to hold x (134 MB).

typedef float f32x4 __attribute__((ext_vector_type(4)));

constexpr int BATCH = 8;
constexpr int C     = 32;
constexpr int FREQ  = 256;
constexpr int TIME  = 512;
constexpr int T4    = TIME / 4;          // 128 float4 per row
constexpr int J     = FREQ / 4;          // 64 f-groups
constexpr int NTHREADS = BATCH * 4 * C * J * T4;   // 2^23 threads
constexpr int BLOCKS   = NTHREADS / 256;           // 32768 blocks

__device__ __forceinline__ f32x4 lerp4(float w, f32x4 a, f32x4 b) {
    return w * a + (1.0f - w) * b;
}

__device__ __forceinline__ void nt_store(f32x4* p, f32x4 v) {
    __builtin_nontemporal_store(v, p);
}

__global__ __launch_bounds__(256) void harmonic_lowering_kernel(
    const f32x4* __restrict__ x, f32x4* __restrict__ out)
{
    int id = blockIdx.x * 256 + threadIdx.x;   // < 2^23

    int tv   = id & (T4 - 1);       // 7 bits
    int rest = id >> 7;
    int j    = rest & (J - 1);      // 6 bits
    rest   >>= 6;
    int c    = rest & (C - 1);      // 5 bits
    rest   >>= 5;
    int k    = rest & 3;            // 2 bits (block-uniform)
    int b    = rest >> 2;           // 3 bits

    const f32x4* __restrict__ base = x + ((b * C + c) * FREQ) * T4 + tv;
    // out channel = k*C + c; rows f = 4j + p
    f32x4* __restrict__ ob = out + ((((b * 4 + k) * C + c) * FREQ) + 4 * j) * T4 + tv;

    if (k == 0) {
        f32x4 g0 = base[(j    ) * T4];
        f32x4 g1 = base[(j + 1) * T4];
        nt_store(ob         , g0);
        nt_store(ob +     T4, lerp4(0.75f, g0, g1));
        nt_store(ob + 2 * T4, lerp4(0.50f, g0, g1));
        nt_store(ob + 3 * T4, lerp4(0.25f, g0, g1));
    } else if (k == 1) {
        f32x4 g0 = base[(2 * j    ) * T4];
        f32x4 g1 = base[(2 * j + 1) * T4];
        f32x4 g2 = base[(2 * j + 2) * T4];
        nt_store(ob         , g0);
        nt_store(ob +     T4, lerp4(0.50f, g0, g1));
        nt_store(ob + 2 * T4, g1);
        nt_store(ob + 3 * T4, lerp4(0.50f, g1, g2));
    } else if (k == 2) {
        f32x4 g0 = base[(3 * j    ) * T4];
        f32x4 g1 = base[(3 * j + 1) * T4];
        f32x4 g2 = base[(3 * j + 2) * T4];
        f32x4 g3 = base[(3 * j + 3) * T4];
        nt_store(ob         , g0);
        nt_store(ob +     T4, lerp4(0.25f, g0, g1));
        nt_store(ob + 2 * T4, lerp4(0.50f, g1, g2));
        nt_store(ob + 3 * T4, lerp4(0.75f, g2, g3));
    } else {
        f32x4 g0 = base[(4 * j    ) * T4];
        f32x4 g1 = base[(4 * j + 1) * T4];
        f32x4 g2 = base[(4 * j + 2) * T4];
        f32x4 g3 = base[(4 * j + 3) * T4];
        nt_store(ob         , g0);
        nt_store(ob +     T4, g1);
        nt_store(ob + 2 * T4, g2);
        nt_store(ob + 3 * T4, g3);
    }
}

extern "C" void kernel_launch(void* const* d_in, const int* in_sizes, int n_in,
                              void* d_out, int out_size, void* d_ws, size_t ws_size,
                              hipStream_t stream) {
    const f32x4* x = (const f32x4*)d_in[0];
    f32x4* out     = (f32x4*)d_out;
    harmonic_lowering_kernel<<<BLOCKS, 256, 0, stream>>>(x, out);
}

// Round 3
// 627.279 us; speedup vs baseline: 1.0315x; 1.0315x over previous
//
#include <hip/hip_runtime.h>

// HarmonicLowering: out[b, k*C+c, f, t] = w*x[b,c,i0,t] + (1-w)*x[b,c,i1,t]
//   prod = f*(k+1); i0 = prod>>2; w = 1 - (prod&3)/4; i1 = min(i0+1, F-1)
// Shapes: x (8,32,256,512) f32 -> out (8,128,256,512) f32.
//
// v3: f-group-of-4 structure from v2 (per-k row sharing, clamp dropped,
// block-uniform k), plus:
//  - NO nontemporal stores: out lines are fully written by coalesced wave
//    stores; going through L2 enables write-combining (the 6.3 TB/s poison
//    fill goes through L2). nt in v2 may have capped write BW.
//  - 2x tv positions per thread (tv and tv+64): doubles independent
//    load/store streams per wave (MLP), halves wave count.
// Per-k row sharing:
//   k=0: rows {j, j+1}        w = 1, .75, .5, .25
//   k=1: rows {2j..2j+2}      w = 1, .5, 1, .5
//   k=2: rows {3j..3j+3}      w = 1, .25, .5, .75
//   k=3: rows {4j..4j+3}      pure copy
// All row indices <= 255, so the min() clamp is provably dead.

typedef float f32x4 __attribute__((ext_vector_type(4)));

constexpr int BATCH = 8;
constexpr int C     = 32;
constexpr int FREQ  = 256;
constexpr int TIME  = 512;
constexpr int T4    = TIME / 4;          // 128 float4 per row
constexpr int TVP   = T4 / 2;            // 64 tv-pairs per row
constexpr int J     = FREQ / 4;          // 64 f-groups
constexpr int NTHREADS = BATCH * 4 * C * J * TVP;  // 2^22 threads
constexpr int BLOCKS   = NTHREADS / 256;           // 16384 blocks

__device__ __forceinline__ f32x4 lerp4(float w, f32x4 a, f32x4 b) {
    return w * a + (1.0f - w) * b;
}

__global__ __launch_bounds__(256) void harmonic_lowering_kernel(
    const f32x4* __restrict__ x, f32x4* __restrict__ out)
{
    int id = blockIdx.x * 256 + threadIdx.x;   // < 2^22

    int tvp  = id & (TVP - 1);      // 6 bits: tv0 = tvp, tv1 = tvp + 64
    int rest = id >> 6;
    int j    = rest & (J - 1);      // 6 bits
    rest   >>= 6;
    int c    = rest & (C - 1);      // 5 bits
    rest   >>= 5;
    int k    = rest & 3;            // 2 bits (block-uniform)
    int b    = rest >> 2;           // 3 bits

    const f32x4* __restrict__ base = x + ((b * C + c) * FREQ) * T4 + tvp;
    // out channel = k*C + c; rows f = 4j + p; columns tvp and tvp+64
    f32x4* __restrict__ ob = out + ((((b * 4 + k) * C + c) * FREQ) + 4 * j) * T4 + tvp;

    if (k == 0) {
        const f32x4* r0 = base + (j    ) * T4;
        const f32x4* r1 = base + (j + 1) * T4;
        f32x4 g0a = r0[0], g0b = r0[TVP];
        f32x4 g1a = r1[0], g1b = r1[TVP];
        ob[0         ] = g0a;                      ob[          TVP] = g0b;
        ob[    T4    ] = lerp4(0.75f, g0a, g1a);   ob[    T4 + TVP] = lerp4(0.75f, g0b, g1b);
        ob[2 * T4    ] = lerp4(0.50f, g0a, g1a);   ob[2 * T4 + TVP] = lerp4(0.50f, g0b, g1b);
        ob[3 * T4    ] = lerp4(0.25f, g0a, g1a);   ob[3 * T4 + TVP] = lerp4(0.25f, g0b, g1b);
    } else if (k == 1) {
        const f32x4* r0 = base + (2 * j    ) * T4;
        const f32x4* r1 = base + (2 * j + 1) * T4;
        const f32x4* r2 = base + (2 * j + 2) * T4;
        f32x4 g0a = r0[0], g0b = r0[TVP];
        f32x4 g1a = r1[0], g1b = r1[TVP];
        f32x4 g2a = r2[0], g2b = r2[TVP];
        ob[0         ] = g0a;                      ob[          TVP] = g0b;
        ob[    T4    ] = lerp4(0.50f, g0a, g1a);   ob[    T4 + TVP] = lerp4(0.50f, g0b, g1b);
        ob[2 * T4    ] = g1a;                      ob[2 * T4 + TVP] = g1b;
        ob[3 * T4    ] = lerp4(0.50f, g1a, g2a);   ob[3 * T4 + TVP] = lerp4(0.50f, g1b, g2b);
    } else if (k == 2) {
        const f32x4* r0 = base + (3 * j    ) * T4;
        const f32x4* r1 = base + (3 * j + 1) * T4;
        const f32x4* r2 = base + (3 * j + 2) * T4;
        const f32x4* r3 = base + (3 * j + 3) * T4;
        f32x4 g0a = r0[0], g0b = r0[TVP];
        f32x4 g1a = r1[0], g1b = r1[TVP];
        f32x4 g2a = r2[0], g2b = r2[TVP];
        f32x4 g3a = r3[0], g3b = r3[TVP];
        ob[0         ] = g0a;                      ob[          TVP] = g0b;
        ob[    T4    ] = lerp4(0.25f, g0a, g1a);   ob[    T4 + TVP] = lerp4(0.25f, g0b, g1b);
        ob[2 * T4    ] = lerp4(0.50f, g1a, g2a);   ob[2 * T4 + TVP] = lerp4(0.50f, g1b, g2b);
        ob[3 * T4    ] = lerp4(0.75f, g2a, g3a);   ob[3 * T4 + TVP] = lerp4(0.75f, g2b, g3b);
    } else {
        const f32x4* r0 = base + (4 * j    ) * T4;
        const f32x4* r1 = base + (4 * j + 1) * T4;
        const f32x4* r2 = base + (4 * j + 2) * T4;
        const f32x4* r3 = base + (4 * j + 3) * T4;
        f32x4 g0a = r0[0], g0b = r0[TVP];
        f32x4 g1a = r1[0], g1b = r1[TVP];
        f32x4 g2a = r2[0], g2b = r2[TVP];
        f32x4 g3a = r3[0], g3b = r3[TVP];
        ob[0         ] = g0a;                      ob[          TVP] = g0b;
        ob[    T4    ] = g1a;                      ob[    T4 + TVP] = g1b;
        ob[2 * T4    ] = g2a;                      ob[2 * T4 + TVP] = g2b;
        ob[3 * T4    ] = g3a;                      ob[3 * T4 + TVP] = g3b;
    }
}

extern "C" void kernel_launch(void* const* d_in, const int* in_sizes, int n_in,
                              void* d_out, int out_size, void* d_ws, size_t ws_size,
                              hipStream_t stream) {
    const f32x4* x = (const f32x4*)d_in[0];
    f32x4* out     = (f32x4*)d_out;
    harmonic_lowering_kernel<<<BLOCKS, 256, 0, stream>>>(x, out);
}